// Round 15
// baseline (75.734 us; speedup 1.0000x reference)
//
#include <hip/hip_runtime.h>
#include <cstddef>
#include <cstdint>

// Problem constants: T=2048, B=8, C=1024, H=16, K=31, P=15
constexpr int T_ = 2048;
constexpr int B_ = 8;
constexpr int C_ = 1024;
constexpr int H_ = 16;
constexpr int K_ = 31;
constexpr int P_ = 15;
constexpr int M_ = T_ * B_;   // 16384
constexpr int N_ = H_ * K_;   // 496
constexpr int NP = 512;       // padded N, slot layout n' = h*32 + k

typedef _Float16 f16x4 __attribute__((ext_vector_type(4)));
typedef _Float16 f16x8 __attribute__((ext_vector_type(8)));
typedef float f32x4 __attribute__((ext_vector_type(4)));

__device__ __forceinline__ void async_cp16(const void* g, void* l) {
    __builtin_amdgcn_global_load_lds(
        (const __attribute__((address_space(1))) void*)g,
        (__attribute__((address_space(3))) void*)l, 16, 0, 0);
}

// ---------------------------------------------------------------------------
// K0: fused convert. X -> Xh fp16; W -> Wh (512x1024 fp16, slot layout
// n' = h*32+k; k==31 rows zero). Identical to round 8 (runs ~85% HBM BW).
// ---------------------------------------------------------------------------
constexpr int XCH = M_ * C_ / 8;    // 2,097,152 f16x8 chunks
constexpr int WCH = NP * C_ / 8;    // 65,536

__global__ __launch_bounds__(256)
void cvt_inputs(const float* __restrict__ X, const float* __restrict__ W,
                _Float16* __restrict__ Xh, _Float16* __restrict__ Wh) {
    const int id = blockIdx.x * 256 + threadIdx.x;
    if (id < XCH) {
        const float4 v0 = *(const float4*)(X + (size_t)id * 8);
        const float4 v1 = *(const float4*)(X + (size_t)id * 8 + 4);
        f16x8 hv;
        hv[0] = (_Float16)v0.x; hv[1] = (_Float16)v0.y;
        hv[2] = (_Float16)v0.z; hv[3] = (_Float16)v0.w;
        hv[4] = (_Float16)v1.x; hv[5] = (_Float16)v1.y;
        hv[6] = (_Float16)v1.z; hv[7] = (_Float16)v1.w;
        *(f16x8*)(Xh + (size_t)id * 8) = hv;
    } else {
        const int j = id - XCH;
        const int n = j >> 7, sp = j & 127;
        const int h = n >> 5, k = n & 31;
        f16x8 hv = {};
        if (k < 31) {
            const float* wp = W + (size_t)(h * 31 + k) * C_ + sp * 8;
            const float4 v0 = *(const float4*)(wp);
            const float4 v1 = *(const float4*)(wp + 4);
            hv[0] = (_Float16)v0.x; hv[1] = (_Float16)v0.y;
            hv[2] = (_Float16)v0.z; hv[3] = (_Float16)v0.w;
            hv[4] = (_Float16)v1.x; hv[5] = (_Float16)v1.y;
            hv[6] = (_Float16)v1.z; hv[7] = (_Float16)v1.w;
        }
        *(f16x8*)(Wh + (size_t)n * C_ + sp * 8) = hv;
    }
}

// ---------------------------------------------------------------------------
// K1: GEMM + per-block softmax -> WSM fp16. Round-8/13 structure with the
// wait-schedule fix: BK=32, BOTH A and B 3-deep. Step t issues {B(t+2),
// A(t+2)}; its end-of-step vmcnt(4) drains only the (t+1) set (issued a
// full k-step earlier) -> staging latency hidden for both operands.
// LDS 48 KB (6 x 8 KB buffers; Ls overlay 34.8 KB fits) -> 3 blocks/CU.
// 4 waves 2x2, wave tile 64x64, 16 MFMA/wave/step, 32 steps.
// ---------------------------------------------------------------------------
__global__ __launch_bounds__(256)
void gemm_softmax(const _Float16* __restrict__ Xh,
                  const _Float16* __restrict__ Wh,
                  _Float16* __restrict__ WSM) {
    __shared__ union {
        struct { _Float16 A[3][128 * 32]; _Float16 B[3][128 * 32]; } s;  // 48 KB
        _Float16 Ls[128 * 136];   // logits overlay (phase-disjoint), 34.8 KB
    } u;

    const int tid = threadIdx.x;
    const int lane = tid & 63;
    const int w = tid >> 6;
    const int wm = (w >> 1) * 64;
    const int wn = (w & 1) * 64;
    const int col = lane & 15;
    const int g = lane >> 4;         // k-chunk 0..3 (8 halves each)

    // XCD-partner swizzle (neutral, harmless): partners share bx.
    const int id = (int)blockIdx.x;
    const int bx = (id & 7) | ((id >> 5) << 3);
    const int by = (id >> 3) & 3;
    const int m0 = bx * 128;
    const int n0 = by * 128;

    // staging: tile = 128 rows x 4 chunks = 512 chunks; 2 A + 2 B per thread.
    // chunk ci -> row r = ci>>2, store-pos cs = ci&3; source holds logical
    // chunk cs ^ (r&3) (both-sides swizzle).
    const _Float16* asrc[2];
    const _Float16* bsrc[2];
#pragma unroll
    for (int p = 0; p < 2; ++p) {
        const int ci = p * 256 + tid;
        const int r = ci >> 2, cs = ci & 3;
        const int cl = cs ^ (r & 3);
        asrc[p] = Xh + (size_t)(m0 + r) * C_ + cl * 8;
        bsrc[p] = Wh + (size_t)(n0 + r) * C_ + cl * 8;
    }

    f32x4 acc[4][4] = {};

#define ISSUE(t_, buf_)                                                   \
    _Pragma("unroll")                                                     \
    for (int p = 0; p < 2; ++p) {                                         \
        const int ci = p * 256 + tid;                                     \
        async_cp16(bsrc[p] + (t_) * 32, &u.s.B[buf_][ci * 8]);            \
    }                                                                     \
    _Pragma("unroll")                                                     \
    for (int p = 0; p < 2; ++p) {                                         \
        const int ci = p * 256 + tid;                                     \
        async_cp16(asrc[p] + (t_) * 32, &u.s.A[buf_][ci * 8]);            \
    }

    // ---- prologue: issue steps 0 and 1; wait step 0 (leave 1 in flight) ----
    ISSUE(0, 0);
    ISSUE(1, 1);
    asm volatile("s_waitcnt vmcnt(4)" ::: "memory");
    __builtin_amdgcn_s_barrier();
    __builtin_amdgcn_sched_barrier(0);

    for (int t = 0; t < 32; ++t) {
        const int cur = t % 3;
        if (t < 30) { const int nb = (t + 2) % 3; ISSUE(t + 2, nb); }

        // ---- compute k-step t: 16 MFMA/wave ----
        f16x8 a[4], b[4];
#pragma unroll
        for (int mf = 0; mf < 4; ++mf) {
            const int row = wm + mf * 16 + col;
            const int c = g ^ (row & 3);
            a[mf] = *(const f16x8*)&u.s.A[cur][row * 32 + c * 8];
        }
#pragma unroll
        for (int nf = 0; nf < 4; ++nf) {
            const int row = wn + nf * 16 + col;
            const int c = g ^ (row & 3);
            b[nf] = *(const f16x8*)&u.s.B[cur][row * 32 + c * 8];
        }
#pragma unroll
        for (int nf = 0; nf < 4; ++nf)
#pragma unroll
            for (int mf = 0; mf < 4; ++mf)
                acc[mf][nf] = __builtin_amdgcn_mfma_f32_16x16x32_f16(
                    a[mf], b[nf], acc[mf][nf], 0, 0, 0);

        // ---- counted wait: drain (t+1)'s set, keep (t+2)'s in flight ----
        if (t < 30) {
            asm volatile("s_waitcnt vmcnt(4)" ::: "memory");
        } else {
            asm volatile("s_waitcnt vmcnt(0)" ::: "memory");
        }
        __builtin_amdgcn_s_barrier();
        __builtin_amdgcn_sched_barrier(0);
    }
#undef ISSUE

    // ---- dump logits to overlay: Ls[row][nl], stride 136 ----
    const int rb = g * 4;
#pragma unroll
    for (int nf = 0; nf < 4; ++nf) {
        const int nl = wn + nf * 16 + col;
#pragma unroll
        for (int mf = 0; mf < 4; ++mf) {
            const int row = wm + mf * 16 + rb;
#pragma unroll
            for (int r = 0; r < 4; ++r)
                u.Ls[(row + r) * 136 + nl] = (_Float16)acc[mf][nf][r];
        }
    }
    __syncthreads();

    // ---- softmax: 512 (row, head-local) tasks, 2 per thread ----
#pragma unroll
    for (int p = 0; p < 2; ++p) {
        const int task = tid + p * 256;
        const int row = task >> 2, hl = task & 3;
        const _Float16* lp = &u.Ls[row * 136 + hl * 32];
        float v[32];
#pragma unroll
        for (int c = 0; c < 4; ++c) {
            const f16x8 ch = *(const f16x8*)(lp + c * 8);
#pragma unroll
            for (int e = 0; e < 8; ++e) v[c * 8 + e] = (float)ch[e];
        }
        float mx = v[0];
#pragma unroll
        for (int k = 1; k < 31; ++k) mx = fmaxf(mx, v[k]);
        float ssum = 0.f;
#pragma unroll
        for (int k = 0; k < 31; ++k) { v[k] = __expf(v[k] - mx); ssum += v[k]; }
        const float inv = 1.f / ssum;
        _Float16* op = WSM + (size_t)(m0 + row) * NP + n0 + hl * 32;
#pragma unroll
        for (int c = 0; c < 4; ++c) {
            f16x8 ov;
#pragma unroll
            for (int e = 0; e < 8; ++e) {
                const int k = c * 8 + e;
                ov[e] = (k < 31) ? (_Float16)(v[k] * inv) : (_Float16)0.f;
            }
            *(f16x8*)(op + c * 8) = ov;
        }
    }
}

// ---------------------------------------------------------------------------
// K2: depthwise dynamic conv, x read as fp16 (Xh). Identical to round 8.
// ---------------------------------------------------------------------------
__global__ __launch_bounds__(256)
void dconv(const _Float16* __restrict__ Xh, const _Float16* __restrict__ WSM,
           float* __restrict__ out) {
    __shared__ float xs[94][64];
    __shared__ float ws[64][36];

    const int tid = threadIdx.x;
    const int t0 = blockIdx.x * 64;
    const int bh = (int)blockIdx.y;
    const int b = bh >> 4, h = bh & 15;

    for (int task = tid; task < 94 * 8; task += 256) {
        const int r = task >> 3, hc = task & 7;
        const int tp = t0 + r - 15;
        f16x8 v = {};
        if (tp >= 0 && tp < T_)
            v = *(const f16x8*)(Xh + ((size_t)tp * B_ + b) * C_ + h * 64 + hc * 8);
        f32x4 lo, hi;
        lo[0] = (float)v[0]; lo[1] = (float)v[1];
        lo[2] = (float)v[2]; lo[3] = (float)v[3];
        hi[0] = (float)v[4]; hi[1] = (float)v[5];
        hi[2] = (float)v[6]; hi[3] = (float)v[7];
        const int c0 = (2 * hc) ^ (r & 7), c1 = (2 * hc + 1) ^ (r & 7);
        *(f32x4*)&xs[r][c0 * 4] = lo;
        *(f32x4*)&xs[r][c1 * 4] = hi;
    }
    {
        const int t = tid >> 2, kc = (tid & 3) * 8;
        const f16x8 wv =
            *(const f16x8*)(WSM + ((size_t)(t0 + t) * B_ + b) * NP + h * 32 + kc);
        f32x4 lo, hi;
        lo[0] = (float)wv[0]; lo[1] = (float)wv[1];
        lo[2] = (float)wv[2]; lo[3] = (float)wv[3];
        hi[0] = (float)wv[4]; hi[1] = (float)wv[5];
        hi[2] = (float)wv[6]; hi[3] = (float)wv[7];
        *(f32x4*)&ws[t][kc] = lo;
        *(f32x4*)&ws[t][kc + 4] = hi;
    }
    __syncthreads();

    const int s = tid & 15;
    const int tg4 = (tid >> 4) * 4;
    f32x4 acc[4] = {};
    f32x4 wc[4];

#pragma unroll
    for (int rr = 0; rr < 34; ++rr) {
        const int r = tg4 + rr;
        const f32x4 xv = *(const f32x4*)&xs[r][(s ^ (r & 7)) * 4];
#pragma unroll
        for (int i = 0; i < 4; ++i) {
            const int k = rr - i;
            if (k < 0 || k > 30) continue;
            if ((k & 3) == 0) wc[i] = *(const f32x4*)&ws[tg4 + i][k];
            acc[i] += wc[i][k & 3] * xv;
        }
    }

#pragma unroll
    for (int i = 0; i < 4; ++i) {
        const int t = t0 + tg4 + i;
        *(f32x4*)(out + ((size_t)t * B_ + b) * C_ + h * 64 + s * 4) = acc[i];
    }
}

// ---------------------------------------------------------------------------
extern "C" void kernel_launch(void* const* d_in, const int* in_sizes, int n_in,
                              void* d_out, int out_size, void* d_ws,
                              size_t ws_size, hipStream_t stream) {
    const float* X = (const float*)d_in[0];
    const float* W = (const float*)d_in[1];
    float* out = (float*)d_out;

    // workspace: Wh (1 MiB) | WSM (16 MiB) | Xh (32 MiB)  = 49 MiB
    _Float16* Wh = (_Float16*)d_ws;
    _Float16* WSM = (_Float16*)((char*)d_ws + (size_t)NP * C_ * 2);
    _Float16* Xh = (_Float16*)((char*)d_ws + (size_t)NP * C_ * 2 +
                               (size_t)M_ * NP * 2);

    cvt_inputs<<<(XCH + WCH) / 256, 256, 0, stream>>>(X, W, Xh, Wh);
    gemm_softmax<<<512, 256, 0, stream>>>(Xh, Wh, WSM);
    dconv<<<dim3(T_ / 64, B_ * H_), 256, 0, stream>>>(Xh, WSM, out);
}

// Round 16
// 70.149 us; speedup vs baseline: 1.0796x; 1.0796x over previous
//
#include <hip/hip_runtime.h>
#include <cstddef>
#include <cstdint>

// Problem constants: T=2048, B=8, C=1024, H=16, K=31, P=15
constexpr int T_ = 2048;
constexpr int B_ = 8;
constexpr int C_ = 1024;
constexpr int H_ = 16;
constexpr int K_ = 31;
constexpr int P_ = 15;
constexpr int M_ = T_ * B_;   // 16384
constexpr int N_ = H_ * K_;   // 496
constexpr int NP = 512;       // padded N, slot layout n' = h*32 + k

typedef _Float16 f16x4 __attribute__((ext_vector_type(4)));
typedef _Float16 f16x8 __attribute__((ext_vector_type(8)));
typedef float f32x4 __attribute__((ext_vector_type(4)));

__device__ __forceinline__ void async_cp16(const void* g, void* l) {
    __builtin_amdgcn_global_load_lds(
        (const __attribute__((address_space(1))) void*)g,
        (__attribute__((address_space(3))) void*)l, 16, 0, 0);
}

// ---------------------------------------------------------------------------
// K0: fused convert. X -> Xh fp16; W -> Wh (512x1024 fp16, slot layout
// n' = h*32+k; k==31 rows zero). Identical to round 8/13.
// ---------------------------------------------------------------------------
constexpr int XCH = M_ * C_ / 8;    // 2,097,152 f16x8 chunks
constexpr int WCH = NP * C_ / 8;    // 65,536

__global__ __launch_bounds__(256)
void cvt_inputs(const float* __restrict__ X, const float* __restrict__ W,
                _Float16* __restrict__ Xh, _Float16* __restrict__ Wh) {
    const int id = blockIdx.x * 256 + threadIdx.x;
    if (id < XCH) {
        const float4 v0 = *(const float4*)(X + (size_t)id * 8);
        const float4 v1 = *(const float4*)(X + (size_t)id * 8 + 4);
        f16x8 hv;
        hv[0] = (_Float16)v0.x; hv[1] = (_Float16)v0.y;
        hv[2] = (_Float16)v0.z; hv[3] = (_Float16)v0.w;
        hv[4] = (_Float16)v1.x; hv[5] = (_Float16)v1.y;
        hv[6] = (_Float16)v1.z; hv[7] = (_Float16)v1.w;
        *(f16x8*)(Xh + (size_t)id * 8) = hv;
    } else {
        const int j = id - XCH;
        const int n = j >> 7, sp = j & 127;
        const int h = n >> 5, k = n & 31;
        f16x8 hv = {};
        if (k < 31) {
            const float* wp = W + (size_t)(h * 31 + k) * C_ + sp * 8;
            const float4 v0 = *(const float4*)(wp);
            const float4 v1 = *(const float4*)(wp + 4);
            hv[0] = (_Float16)v0.x; hv[1] = (_Float16)v0.y;
            hv[2] = (_Float16)v0.z; hv[3] = (_Float16)v0.w;
            hv[4] = (_Float16)v1.x; hv[5] = (_Float16)v1.y;
            hv[6] = (_Float16)v1.z; hv[7] = (_Float16)v1.w;
        }
        *(f16x8*)(Wh + (size_t)n * C_ + sp * 8) = hv;
    }
}

// ---------------------------------------------------------------------------
// K1: GEMM -> raw f16 logits Lg (slot layout). Round-13 k-loop verbatim
// (counted vmcnt, A 3-deep, B 2-deep, BK=64, 80 KB LDS, 2 blocks/CU).
// Epilogue: direct f16 stores of acc (no LDS overlay, no barriers, no exp —
// softmax moved to dconv where it's free).
// ---------------------------------------------------------------------------
__global__ __launch_bounds__(256)
void gemm_logits(const _Float16* __restrict__ Xh,
                 const _Float16* __restrict__ Wh,
                 _Float16* __restrict__ Lg) {
    __shared__ _Float16 As[3][128 * 64];   // 48 KB
    __shared__ _Float16 Bs[2][128 * 64];   // 32 KB

    const int tid = threadIdx.x;
    const int lane = tid & 63;
    const int w = tid >> 6;
    const int wm = (w >> 1) * 64;
    const int wn = (w & 1) * 64;
    const int col = lane & 15;
    const int g = lane >> 4;

    const int id = (int)blockIdx.x;
    const int bx = (id & 7) | ((id >> 5) << 3);
    const int by = (id >> 3) & 3;
    const int m0 = bx * 128;
    const int n0 = by * 128;

    const _Float16* asrc[4];
    const _Float16* bsrc[4];
#pragma unroll
    for (int p = 0; p < 4; ++p) {
        const int ci = p * 256 + tid;
        const int r = ci >> 3, cs = ci & 7;
        const int cl = cs ^ (r & 7);
        asrc[p] = Xh + (size_t)(m0 + r) * C_ + cl * 8;
        bsrc[p] = Wh + (size_t)(n0 + r) * C_ + cl * 8;
    }

    f32x4 acc[4][4] = {};

#pragma unroll
    for (int p = 0; p < 4; ++p) {
        const int ci = p * 256 + tid;
        async_cp16(asrc[p], &As[0][ci * 8]);
    }
#pragma unroll
    for (int p = 0; p < 4; ++p) {
        const int ci = p * 256 + tid;
        async_cp16(bsrc[p], &Bs[0][ci * 8]);
    }
#pragma unroll
    for (int p = 0; p < 4; ++p) {
        const int ci = p * 256 + tid;
        async_cp16(asrc[p] + 64, &As[1][ci * 8]);
    }
    asm volatile("s_waitcnt vmcnt(4)" ::: "memory");
    __builtin_amdgcn_s_barrier();
    __builtin_amdgcn_sched_barrier(0);

    for (int t = 0; t < 16; ++t) {
        const int ca = t % 3, cb = t & 1;
        if (t < 15) {
            const int k1 = (t + 1) * 64;
#pragma unroll
            for (int p = 0; p < 4; ++p) {
                const int ci = p * 256 + tid;
                async_cp16(bsrc[p] + k1, &Bs[cb ^ 1][ci * 8]);
            }
        }
        if (t < 14) {
            const int k2 = (t + 2) * 64;
            const int ca2 = (t + 2) % 3;
#pragma unroll
            for (int p = 0; p < 4; ++p) {
                const int ci = p * 256 + tid;
                async_cp16(asrc[p] + k2, &As[ca2][ci * 8]);
            }
        }

        f16x8 a[2][4], b[2][4];
#pragma unroll
        for (int kk = 0; kk < 2; ++kk) {
#pragma unroll
            for (int mf = 0; mf < 4; ++mf) {
                const int row = wm + mf * 16 + col;
                const int c = ((kk << 2) | g) ^ (row & 7);
                a[kk][mf] = *(const f16x8*)&As[ca][row * 64 + c * 8];
            }
#pragma unroll
            for (int nf = 0; nf < 4; ++nf) {
                const int row = wn + nf * 16 + col;
                const int c = ((kk << 2) | g) ^ (row & 7);
                b[kk][nf] = *(const f16x8*)&Bs[cb][row * 64 + c * 8];
            }
        }
#pragma unroll
        for (int kk = 0; kk < 2; ++kk)
#pragma unroll
            for (int nf = 0; nf < 4; ++nf)
#pragma unroll
                for (int mf = 0; mf < 4; ++mf)
                    acc[mf][nf] = __builtin_amdgcn_mfma_f32_16x16x32_f16(
                        a[kk][mf], b[kk][nf], acc[kk ? mf : mf][nf], 0, 0, 0);

        if (t < 14) {
            asm volatile("s_waitcnt vmcnt(4)" ::: "memory");
        } else {
            asm volatile("s_waitcnt vmcnt(0)" ::: "memory");
        }
        __builtin_amdgcn_s_barrier();
        __builtin_amdgcn_sched_barrier(0);
    }

    // ---- epilogue: raw f16 logits straight to global (slot layout) ----
    const int rb = g * 4;
#pragma unroll
    for (int nf = 0; nf < 4; ++nf) {
        const int nl = wn + nf * 16 + col;
#pragma unroll
        for (int mf = 0; mf < 4; ++mf) {
            const int row = wm + mf * 16 + rb;
#pragma unroll
            for (int r = 0; r < 4; ++r)
                Lg[(size_t)(m0 + row + r) * NP + n0 + nl] =
                    (_Float16)acc[mf][nf][r];
        }
    }
}

// ---------------------------------------------------------------------------
// K2: softmax + depthwise dynamic conv. Round-13 conv structure; NEW: stages
// raw logits into ws16[64][40] f16, softmaxes in-place (1 wave, hidden under
// memory phase at 16 blocks/CU), conv weights converted f16->f32 at use.
// ---------------------------------------------------------------------------
__global__ __launch_bounds__(256)
void dconv(const _Float16* __restrict__ Xh, const _Float16* __restrict__ Lg,
           float* __restrict__ out) {
    __shared__ float xs[94][64];           // 24 KB
    __shared__ _Float16 ws16[64][40];      // 5 KB (row stride 80 B, 16B-aligned)

    const int tid = threadIdx.x;
    const int t0 = blockIdx.x * 64;
    const int bh = (int)blockIdx.y;
    const int b = bh >> 4, h = bh & 15;

    // stage x window rows t0-15 .. t0+78: f16x8 loads -> 2 swizzled f32x4
    for (int task = tid; task < 94 * 8; task += 256) {
        const int r = task >> 3, hc = task & 7;
        const int tp = t0 + r - 15;
        f16x8 v = {};
        if (tp >= 0 && tp < T_)
            v = *(const f16x8*)(Xh + ((size_t)tp * B_ + b) * C_ + h * 64 + hc * 8);
        f32x4 lo, hi;
        lo[0] = (float)v[0]; lo[1] = (float)v[1];
        lo[2] = (float)v[2]; lo[3] = (float)v[3];
        hi[0] = (float)v[4]; hi[1] = (float)v[5];
        hi[2] = (float)v[6]; hi[3] = (float)v[7];
        const int c0 = (2 * hc) ^ (r & 7), c1 = (2 * hc + 1) ^ (r & 7);
        *(f32x4*)&xs[r][c0 * 4] = lo;
        *(f32x4*)&xs[r][c1 * 4] = hi;
    }
    // stage raw logits (f16 copy, one f16x8 per thread)
    {
        const int t = tid >> 2, kc = (tid & 3) * 8;
        const f16x8 wv =
            *(const f16x8*)(Lg + ((size_t)(t0 + t) * B_ + b) * NP + h * 32 + kc);
        *(f16x8*)&ws16[t][kc] = wv;
    }
    __syncthreads();

    // in-LDS softmax: one row per thread, tid < 64 (overlapped across blocks)
    if (tid < 64) {
        float v[31];
        float mx = -1e30f;
#pragma unroll
        for (int k = 0; k < 31; ++k) {
            v[k] = (float)ws16[tid][k];
            mx = fmaxf(mx, v[k]);
        }
        float ssum = 0.f;
#pragma unroll
        for (int k = 0; k < 31; ++k) { v[k] = __expf(v[k] - mx); ssum += v[k]; }
        const float inv = 1.f / ssum;
#pragma unroll
        for (int k = 0; k < 31; ++k) ws16[tid][k] = (_Float16)(v[k] * inv);
    }
    __syncthreads();

    const int s = tid & 15;
    const int tg4 = (tid >> 4) * 4;
    f32x4 acc[4] = {};
    f32x4 wc[4];

#pragma unroll
    for (int rr = 0; rr < 34; ++rr) {
        const int r = tg4 + rr;
        const f32x4 xv = *(const f32x4*)&xs[r][(s ^ (r & 7)) * 4];
#pragma unroll
        for (int i = 0; i < 4; ++i) {
            const int k = rr - i;
            if (k < 0 || k > 30) continue;
            if ((k & 3) == 0) {
                const f16x4 wq = *(const f16x4*)&ws16[tg4 + i][k];
                wc[i][0] = (float)wq[0]; wc[i][1] = (float)wq[1];
                wc[i][2] = (float)wq[2]; wc[i][3] = (float)wq[3];
            }
            acc[i] += wc[i][k & 3] * xv;
        }
    }

#pragma unroll
    for (int i = 0; i < 4; ++i) {
        const int t = t0 + tg4 + i;
        *(f32x4*)(out + ((size_t)t * B_ + b) * C_ + h * 64 + s * 4) = acc[i];
    }
}

// ---------------------------------------------------------------------------
extern "C" void kernel_launch(void* const* d_in, const int* in_sizes, int n_in,
                              void* d_out, int out_size, void* d_ws,
                              size_t ws_size, hipStream_t stream) {
    const float* X = (const float*)d_in[0];
    const float* W = (const float*)d_in[1];
    float* out = (float*)d_out;

    // workspace: Wh (1 MiB) | Lg (16 MiB) | Xh (32 MiB)  = 49 MiB
    _Float16* Wh = (_Float16*)d_ws;
    _Float16* Lg = (_Float16*)((char*)d_ws + (size_t)NP * C_ * 2);
    _Float16* Xh = (_Float16*)((char*)d_ws + (size_t)NP * C_ * 2 +
                               (size_t)M_ * NP * 2);

    cvt_inputs<<<(XCH + WCH) / 256, 256, 0, stream>>>(X, W, Xh, Wh);
    gemm_logits<<<512, 256, 0, stream>>>(Xh, Wh, Lg);
    dconv<<<dim3(T_ / 64, B_ * H_), 256, 0, stream>>>(Xh, Lg, out);
}